// Round 2
// baseline (2317.015 us; speedup 1.0000x reference)
//
#include <hip/hip_runtime.h>

// ============================================================================
// Wired CfC (NCP) scan, B=256 x T=1024, 3 layers (hid 135/89/32) + final FC.
//
// Round 2 fix: masks are BOOLEAN in the reference -> harness uploads them as
// int32 ("integer -> const int*"), not bytes. Round 1 read them as uint8,
// which kept only every 4th weight (absmax 1.12). Now read as uint32 with a
// !=0 test (also correct if the harness uploaded float 0.0/1.0 bit patterns).
//
// Design: persistent-RNN, 256 blocks x 256 threads (1 batch row per block,
// 1 thread per output unit, 4 waves = 1 wave/SIMD).
//  - Weights (W1*mask, W2*mask, Wa+Wb) pre-folded to f16 pairs in VGPRs
//    (3 x 112 half2 = 336 VGPRs/thread).
//  - Per tick: 28 x (ds_read_b128 broadcast of xcat + 12 v_dot2_f32_f16),
//    then fast tanh/sigmoid (v_exp_f32 + v_rcp_f32) + gate blend in-thread.
//  - Layers pipelined across timesteps (layer l computes timestep tick-l)
//    -> exactly ONE __syncthreads per tick. xcat in ping-pong LDS (f16).
//  - x(t) prefetched 2 ticks ahead by threads 192..255 (reg-buffered).
//  - h kept fp32 for the final 256x256 FC epilogue.
// Theory: 152k MACs/CU/tick at 256 MAC/cyc (dot2) = 594 cyc floor -> ~253us;
// expect ~350-450us with overheads. MFMA rejected: batch/block <=16 forces
// ~339 MFMA tiles/CU/tick = ~685ns/tick (~700us).
// ============================================================================

typedef _Float16 half2v __attribute__((ext_vector_type(2)));
typedef _Float16 half8v __attribute__((ext_vector_type(8)));

#define NBLK   256
#define NTHR   256
#define TSTEPS 1024
#define KPAD   224
#define NKB    28      // KPAD / 8

struct Ptrs {
    const float* x;
    const unsigned int* msk[3];   // bool in reference -> int32 on device
    const float* W1[3];
    const float* W2[3];
    const float* Wa[3];
    const float* Wb[3];
    const float* b1[3];
    const float* b2[3];
    const float* ba[3];
    const float* bb[3];
    const float* fcW;
    const float* fcb;
};

__device__ __forceinline__ float fexp2(float x) {
#if __has_builtin(__builtin_amdgcn_exp2f)
    return __builtin_amdgcn_exp2f(x);
#else
    return exp2f(x);
#endif
}
__device__ __forceinline__ float frcp(float x) {
#if __has_builtin(__builtin_amdgcn_rcpf)
    return __builtin_amdgcn_rcpf(x);
#else
    return 1.0f / x;
#endif
}
// sigmoid(x) = 1/(1+2^(-x*log2e)); tanh(x) = 2/(1+2^(-2x*log2e)) - 1
__device__ __forceinline__ float fsig(float x) {
    return frcp(1.0f + fexp2(-1.442695041f * x));
}
__device__ __forceinline__ float ftanh(float x) {
    return 2.0f * frcp(1.0f + fexp2(-2.885390082f * x)) - 1.0f;
}

#if __has_builtin(__builtin_amdgcn_fdot2)
#define FD(a, b, c) __builtin_amdgcn_fdot2((a), (b), (c), false)
#else
__device__ __forceinline__ float fd_fallback(half2v a, half2v b, float c) {
    return c + (float)a[0] * (float)b[0] + (float)a[1] * (float)b[1];
}
#define FD(a, b, c) fd_fallback((a), (b), (c))
#endif

__global__ __launch_bounds__(NTHR, 1) void cfc_kernel(Ptrs P, float* __restrict__ out) {
    // xc[parity][layer][k] : f16 concat inputs per layer, zero-padded to KPAD.
    __shared__ __align__(16) _Float16 xc[2][3][KPAD];
    __shared__ __align__(16) float hn[256];

    const int tid = threadIdx.x;
    const int b   = blockIdx.x;

    // ---- thread role: one output unit ----
    int L, n;
    if (tid < 135)      { L = 0; n = tid; }
    else if (tid < 224) { L = 1; n = tid - 135; }
    else                { L = 2; n = tid - 224; }
    const int K    = (L == 0) ? 199 : ((L == 1) ? 224 : 121);
    const int HOFF = (L == 0) ? 0   : ((L == 1) ? 135 : 224);

    // ---- zero LDS (padding regions must read as 0.0) ----
    {
        int* z = (int*)&xc[0][0][0];
        for (int i = tid; i < 2 * 3 * KPAD / 2; i += NTHR) z[i] = 0;
    }
    __syncthreads();

    // ---- x staging: threads 192..255 own one of the 64 input features ----
    const int xlane = tid - 192;
    float xpend = 0.0f;
    if (xlane >= 0) {
        xc[0][0][xlane] = (_Float16)P.x[((size_t)b * TSTEPS + 0) * 64 + xlane];
        xpend           = P.x[((size_t)b * TSTEPS + 1) * 64 + xlane];
    }

    // ---- weight preload: fold mask into W1/W2, fold Wa+Wb; cast to f16 ----
    const float* W1p        = P.W1[L];
    const float* W2p        = P.W2[L];
    const float* Wap        = P.Wa[L];
    const float* Wbp        = P.Wb[L];
    const unsigned int* mkp = P.msk[L];
    const int nK = n * K;

    half2v wr1[KPAD / 2], wr2[KPAD / 2], wra[KPAD / 2];
#pragma unroll
    for (int i = 0; i < KPAD / 2; ++i) {
        const int k0 = 2 * i, k1 = 2 * i + 1;
        float u0 = 0.f, u1 = 0.f, v0 = 0.f, v1 = 0.f, a0 = 0.f, a1 = 0.f;
        if (k0 < K) {
            const int idx = nK + k0;
            const float mm = (mkp[idx] != 0u) ? 1.0f : 0.0f;
            u0 = W1p[idx] * mm;
            v0 = W2p[idx] * mm;
            a0 = Wap[idx] + Wbp[idx];
        }
        if (k1 < K) {
            const int idx = nK + k1;
            const float mm = (mkp[idx] != 0u) ? 1.0f : 0.0f;
            u1 = W1p[idx] * mm;
            v1 = W2p[idx] * mm;
            a1 = Wap[idx] + Wbp[idx];
        }
        wr1[i] = half2v{(_Float16)u0, (_Float16)u1};
        wr2[i] = half2v{(_Float16)v0, (_Float16)v1};
        wra[i] = half2v{(_Float16)a0, (_Float16)a1};
    }
    const float bv1 = P.b1[L][n];
    const float bv2 = P.b2[L][n];
    const float bva = P.ba[L][n] + P.bb[L][n];
    __syncthreads();

    // ---- main scan: layer L computes timestep (tick - L); 1 barrier/tick ----
    for (int tick = 0; tick < TSTEPS + 2; ++tick) {
        // stage x(tick+1) (loaded 1 tick ago), prefetch x(tick+2)
        if (xlane >= 0) {
            if (tick + 1 < TSTEPS)
                xc[(tick + 1) & 1][0][xlane] = (_Float16)xpend;
            if (tick + 2 < TSTEPS)
                xpend = P.x[((size_t)b * TSTEPS + (tick + 2)) * 64 + xlane];
        }

        const int s = tick - L;
        if (s >= 0 && s < TSTEPS) {
            const _Float16* src = &xc[s & 1][L][0];
            float ac00 = 0.f, ac01 = 0.f, ac10 = 0.f, ac11 = 0.f, ac20 = 0.f, ac21 = 0.f;
#pragma unroll
            for (int kb = 0; kb < NKB; ++kb) {
                const half8v xv = *(const half8v*)(src + kb * 8);
                const half2v x0 = {xv[0], xv[1]};
                const half2v x1 = {xv[2], xv[3]};
                const half2v x2 = {xv[4], xv[5]};
                const half2v x3 = {xv[6], xv[7]};
                const int k4 = kb * 4;
                ac00 = FD(x0, wr1[k4 + 0], ac00);
                ac10 = FD(x0, wr2[k4 + 0], ac10);
                ac20 = FD(x0, wra[k4 + 0], ac20);
                ac01 = FD(x1, wr1[k4 + 1], ac01);
                ac11 = FD(x1, wr2[k4 + 1], ac11);
                ac21 = FD(x1, wra[k4 + 1], ac21);
                ac00 = FD(x2, wr1[k4 + 2], ac00);
                ac10 = FD(x2, wr2[k4 + 2], ac10);
                ac20 = FD(x2, wra[k4 + 2], ac20);
                ac01 = FD(x3, wr1[k4 + 3], ac01);
                ac11 = FD(x3, wr2[k4 + 3], ac11);
                ac21 = FD(x3, wra[k4 + 3], ac21);
            }
            const float p1 = ac00 + ac01 + bv1;
            const float p2 = ac10 + ac11 + bv2;
            const float pa = ac20 + ac21 + bva;
            const float f1 = ftanh(p1);
            const float f2 = ftanh(p2);
            const float tg = fsig(pa);
            const float h  = f1 + tg * (f2 - f1);
            const _Float16 hv = (_Float16)h;

            const int pA = s & 1;        // consumer at timestep s (next layer)
            const int pB = (s + 1) & 1;  // consumer at timestep s+1 (own recurrence)
            if (L == 0) {
                xc[pA][1][n]       = hv;  // -> layer1 input part
                xc[pB][0][64 + n]  = hv;  // -> own recurrent part
            } else if (L == 1) {
                xc[pA][2][n]       = hv;  // -> layer2 input part
                xc[pB][1][135 + n] = hv;  // -> own recurrent part
            } else {
                xc[pB][2][89 + n]  = hv;  // -> own recurrent part
            }
            if (s == TSTEPS - 1) hn[HOFF + n] = h;  // fp32 final state
        }
        __syncthreads();
    }

    // ---- FC epilogue: out[b][o] = dot(hn, fcW[o,:]) + fcb[o] ----
    {
        const int o = tid;
        const float4* wr = (const float4*)(P.fcW + (size_t)o * 256);
        const float4* hr = (const float4*)hn;
        float acc = P.fcb[o];
#pragma unroll 8
        for (int d = 0; d < 64; ++d) {
            const float4 a = hr[d];
            const float4 w = wr[d];
            acc += a.x * w.x + a.y * w.y + a.z * w.z + a.w * w.w;
        }
        out[(size_t)b * 256 + o] = acc;
    }
}

extern "C" void kernel_launch(void* const* d_in, const int* in_sizes, int n_in,
                              void* d_out, int out_size, void* d_ws, size_t ws_size,
                              hipStream_t stream) {
    (void)in_sizes; (void)n_in; (void)out_size; (void)d_ws; (void)ws_size;
    Ptrs P;
    P.x = (const float*)d_in[0];
    for (int l = 0; l < 3; ++l) {
        const int base = 1 + l * 9;
        P.msk[l] = (const unsigned int*)d_in[base + 0];
        P.W1[l]  = (const float*)d_in[base + 1];
        P.W2[l]  = (const float*)d_in[base + 2];
        P.Wa[l]  = (const float*)d_in[base + 3];
        P.Wb[l]  = (const float*)d_in[base + 4];
        P.b1[l]  = (const float*)d_in[base + 5];
        P.b2[l]  = (const float*)d_in[base + 6];
        P.ba[l]  = (const float*)d_in[base + 7];
        P.bb[l]  = (const float*)d_in[base + 8];
    }
    P.fcW = (const float*)d_in[28];
    P.fcb = (const float*)d_in[29];

    hipLaunchKernelGGL(cfc_kernel, dim3(NBLK), dim3(NTHR), 0, stream,
                       P, (float*)d_out);
}

// Round 3
// 1471.086 us; speedup vs baseline: 1.5750x; 1.5750x over previous
//
#include <hip/hip_runtime.h>

// ============================================================================
// Wired CfC (NCP) scan, B=256 x T=1024, 3 layers (hid 135/89/32) + final FC.
//
// Round 3: fix the VGPR spill found in round 2 (VGPR_Count=256 cap hit,
// WRITE_SIZE=135MB of scratch traffic in the scan loop). K dimension is now
// SPLIT ACROSS EVEN/ODD LANE PAIRS: 512 threads/block, pair tid>>1 = output
// unit, tid&1 = which half of K (112 of KPAD=224). Per-thread weights drop
// 336 -> 168 half2 VGPRs (~200 total, under the 256 arch-VGPR cap). Partial
// sums combine via __shfl_xor(.,1) in-wave. 8 waves/CU (2/SIMD).
//
// Unchanged: persistent-RNN (1 batch row/block), masked W1/W2 + folded Wa+Wb
// pre-cast to f16 in VGPRs, v_dot2_f32_f16 inner loop, layers pipelined
// across timesteps (1 barrier/tick), ping-pong f16 xcat in LDS, fast
// tanh/sigmoid via exp2+rcp, fp32 h for the FC epilogue.
// VALU floor: 672 cyc/tick -> 287us; predict 380-550us.
// ============================================================================

typedef _Float16 half2v __attribute__((ext_vector_type(2)));
typedef _Float16 half8v __attribute__((ext_vector_type(8)));

#define NBLK   256
#define NTHR   512
#define TSTEPS 1024
#define KPAD   224
#define KHALF  112
#define NKB    14      // KHALF / 8 blocks per lane

struct Ptrs {
    const float* x;
    const unsigned int* msk[3];   // bool in reference -> int32 on device
    const float* W1[3];
    const float* W2[3];
    const float* Wa[3];
    const float* Wb[3];
    const float* b1[3];
    const float* b2[3];
    const float* ba[3];
    const float* bb[3];
    const float* fcW;
    const float* fcb;
};

__device__ __forceinline__ float fexp2(float x) {
#if __has_builtin(__builtin_amdgcn_exp2f)
    return __builtin_amdgcn_exp2f(x);
#else
    return exp2f(x);
#endif
}
__device__ __forceinline__ float frcp(float x) {
#if __has_builtin(__builtin_amdgcn_rcpf)
    return __builtin_amdgcn_rcpf(x);
#else
    return 1.0f / x;
#endif
}
// sigmoid(x) = 1/(1+2^(-x*log2e)); tanh(x) = 2/(1+2^(-2x*log2e)) - 1
__device__ __forceinline__ float fsig(float x) {
    return frcp(1.0f + fexp2(-1.442695041f * x));
}
__device__ __forceinline__ float ftanh(float x) {
    return 2.0f * frcp(1.0f + fexp2(-2.885390082f * x)) - 1.0f;
}

#if __has_builtin(__builtin_amdgcn_fdot2)
#define FD(a, b, c) __builtin_amdgcn_fdot2((a), (b), (c), false)
#else
__device__ __forceinline__ float fd_fallback(half2v a, half2v b, float c) {
    return c + (float)a[0] * (float)b[0] + (float)a[1] * (float)b[1];
}
#define FD(a, b, c) fd_fallback((a), (b), (c))
#endif

__global__ __launch_bounds__(NTHR, 2) void cfc_kernel(Ptrs P, float* __restrict__ out) {
    // xc[parity][layer][k] : f16 concat inputs per layer, zero-padded to KPAD.
    __shared__ __align__(16) _Float16 xc[2][3][KPAD];
    __shared__ __align__(16) float hn[256];

    const int tid  = threadIdx.x;
    const int b    = blockIdx.x;
    const int pair = tid >> 1;   // output unit 0..255
    const int half = tid & 1;    // which K-half this lane owns

    // ---- pair role: one output unit ----
    int L, n;
    if (pair < 135)      { L = 0; n = pair; }
    else if (pair < 224) { L = 1; n = pair - 135; }
    else                 { L = 2; n = pair - 224; }
    const int K    = (L == 0) ? 199 : ((L == 1) ? 224 : 121);
    const int HOFF = (L == 0) ? 0   : ((L == 1) ? 135 : 224);

    // ---- zero LDS (padding regions must read as 0.0) ----
    {
        int* z = (int*)&xc[0][0][0];
        for (int i = tid; i < 2 * 3 * KPAD / 2; i += NTHR) z[i] = 0;
    }
    __syncthreads();

    // ---- x staging: threads 448..511 own one of the 64 input features ----
    const int xlane = tid - 448;
    float xpend = 0.0f;
    if (xlane >= 0) {
        xc[0][0][xlane] = (_Float16)P.x[((size_t)b * TSTEPS + 0) * 64 + xlane];
        xpend           = P.x[((size_t)b * TSTEPS + 1) * 64 + xlane];
    }

    // ---- weight preload: this lane's K-half; fold mask, fold Wa+Wb; f16 ----
    const float* W1p        = P.W1[L];
    const float* W2p        = P.W2[L];
    const float* Wap        = P.Wa[L];
    const float* Wbp        = P.Wb[L];
    const unsigned int* mkp = P.msk[L];
    const int nK   = n * K;
    const int koff = half * KHALF;

    half2v wr1[KHALF / 2], wr2[KHALF / 2], wra[KHALF / 2];
#pragma unroll
    for (int i = 0; i < KHALF / 2; ++i) {
        const int k0 = koff + 2 * i, k1 = koff + 2 * i + 1;
        float u0 = 0.f, u1 = 0.f, v0 = 0.f, v1 = 0.f, a0 = 0.f, a1 = 0.f;
        if (k0 < K) {
            const int idx = nK + k0;
            const float mm = (mkp[idx] != 0u) ? 1.0f : 0.0f;
            u0 = W1p[idx] * mm;
            v0 = W2p[idx] * mm;
            a0 = Wap[idx] + Wbp[idx];
        }
        if (k1 < K) {
            const int idx = nK + k1;
            const float mm = (mkp[idx] != 0u) ? 1.0f : 0.0f;
            u1 = W1p[idx] * mm;
            v1 = W2p[idx] * mm;
            a1 = Wap[idx] + Wbp[idx];
        }
        wr1[i] = half2v{(_Float16)u0, (_Float16)u1};
        wr2[i] = half2v{(_Float16)v0, (_Float16)v1};
        wra[i] = half2v{(_Float16)a0, (_Float16)a1};
    }
    const float bv1 = P.b1[L][n];
    const float bv2 = P.b2[L][n];
    const float bva = P.ba[L][n] + P.bb[L][n];
    __syncthreads();

    // ---- main scan: layer L computes timestep (tick - L); 1 barrier/tick ----
    for (int tick = 0; tick < TSTEPS + 2; ++tick) {
        // stage x(tick+1) (loaded 1 tick ago), prefetch x(tick+2)
        if (xlane >= 0) {
            if (tick + 1 < TSTEPS)
                xc[(tick + 1) & 1][0][xlane] = (_Float16)xpend;
            if (tick + 2 < TSTEPS)
                xpend = P.x[((size_t)b * TSTEPS + (tick + 2)) * 64 + xlane];
        }

        const int s = tick - L;
        if (s >= 0 && s < TSTEPS) {
            const _Float16* src = &xc[s & 1][L][koff];
            float ac00 = 0.f, ac01 = 0.f, ac10 = 0.f, ac11 = 0.f, ac20 = 0.f, ac21 = 0.f;
#pragma unroll
            for (int kb = 0; kb < NKB; ++kb) {
                const half8v xv = *(const half8v*)(src + kb * 8);
                const half2v x0 = {xv[0], xv[1]};
                const half2v x1 = {xv[2], xv[3]};
                const half2v x2 = {xv[4], xv[5]};
                const half2v x3 = {xv[6], xv[7]};
                const int k4 = kb * 4;
                ac00 = FD(x0, wr1[k4 + 0], ac00);
                ac10 = FD(x0, wr2[k4 + 0], ac10);
                ac20 = FD(x0, wra[k4 + 0], ac20);
                ac01 = FD(x1, wr1[k4 + 1], ac01);
                ac11 = FD(x1, wr2[k4 + 1], ac11);
                ac21 = FD(x1, wra[k4 + 1], ac21);
                ac00 = FD(x2, wr1[k4 + 2], ac00);
                ac10 = FD(x2, wr2[k4 + 2], ac10);
                ac20 = FD(x2, wra[k4 + 2], ac20);
                ac01 = FD(x3, wr1[k4 + 3], ac01);
                ac11 = FD(x3, wr2[k4 + 3], ac11);
                ac21 = FD(x3, wra[k4 + 3], ac21);
            }
            // combine the two K-halves (pairs are adjacent lanes in-wave)
            float s1 = ac00 + ac01;
            float s2 = ac10 + ac11;
            float sa = ac20 + ac21;
            s1 += __shfl_xor(s1, 1, 64);
            s2 += __shfl_xor(s2, 1, 64);
            sa += __shfl_xor(sa, 1, 64);
            // both lanes now hold identical sums -> identical h
            const float f1 = ftanh(s1 + bv1);
            const float f2 = ftanh(s2 + bv2);
            const float tg = fsig(sa + bva);
            const float h  = f1 + tg * (f2 - f1);
            const _Float16 hv = (_Float16)h;

            const int pA = s & 1;        // consumer at timestep s (next layer)
            const int pB = (s + 1) & 1;  // consumer at timestep s+1 (own recurrence)
            // split the two stores across the lane pair
            if (half == 0) {
                if (L == 0)      xc[pA][1][n] = hv;        // -> layer1 input part
                else if (L == 1) xc[pA][2][n] = hv;        // -> layer2 input part
                if (s == TSTEPS - 1) hn[HOFF + n] = h;     // fp32 final state
            } else {
                if (L == 0)      xc[pB][0][64 + n]  = hv;  // own recurrence
                else if (L == 1) xc[pB][1][135 + n] = hv;
                else             xc[pB][2][89 + n]  = hv;
            }
        }
        __syncthreads();
    }

    // ---- FC epilogue: out[b][o] = dot(hn, fcW[o,:]) + fcb[o], K-split pair ----
    {
        const int o = pair;
        const float4* wr = (const float4*)(P.fcW + (size_t)o * 256 + half * 128);
        const float4* hr = (const float4*)(hn + half * 128);
        float acc = half ? 0.0f : P.fcb[o];
#pragma unroll 8
        for (int d = 0; d < 32; ++d) {
            const float4 a = hr[d];
            const float4 w = wr[d];
            acc += a.x * w.x + a.y * w.y + a.z * w.z + a.w * w.w;
        }
        acc += __shfl_xor(acc, 1, 64);
        if (half == 0) out[(size_t)b * 256 + o] = acc;
    }
}

extern "C" void kernel_launch(void* const* d_in, const int* in_sizes, int n_in,
                              void* d_out, int out_size, void* d_ws, size_t ws_size,
                              hipStream_t stream) {
    (void)in_sizes; (void)n_in; (void)out_size; (void)d_ws; (void)ws_size;
    Ptrs P;
    P.x = (const float*)d_in[0];
    for (int l = 0; l < 3; ++l) {
        const int base = 1 + l * 9;
        P.msk[l] = (const unsigned int*)d_in[base + 0];
        P.W1[l]  = (const float*)d_in[base + 1];
        P.W2[l]  = (const float*)d_in[base + 2];
        P.Wa[l]  = (const float*)d_in[base + 3];
        P.Wb[l]  = (const float*)d_in[base + 4];
        P.b1[l]  = (const float*)d_in[base + 5];
        P.b2[l]  = (const float*)d_in[base + 6];
        P.ba[l]  = (const float*)d_in[base + 7];
        P.bb[l]  = (const float*)d_in[base + 8];
    }
    P.fcW = (const float*)d_in[28];
    P.fcb = (const float*)d_in[29];

    hipLaunchKernelGGL(cfc_kernel, dim3(NBLK), dim3(NTHR), 0, stream,
                       P, (float*)d_out);
}

// Round 4
// 1463.102 us; speedup vs baseline: 1.5836x; 1.0055x over previous
//
#include <hip/hip_runtime.h>

// ============================================================================
// Wired CfC (NCP) scan, B=256 x T=1024, 3 layers (hid 135/89/32) + final FC.
//
// Round 4: round 3 still spilled (VGPR_Count=128, WRITE_SIZE=68MB): the
// backend budgeted registers for 4 waves/EU even though grid=256 blocks on
// 256 CUs means only 1 block (8 waves) per CU is ever resident. Pin the
// budget with amdgpu_waves_per_eu(2,2): min=max=2 waves/EU -> 256-VGPR
// allocator budget, no spill-for-occupancy. Per-thread need ~200 regs
// (3 x 56 half2 weights + accumulators) fits.
//
// Design: persistent-RNN, 256 blocks x 512 threads (1 batch row per block),
// output unit = tid>>1, K-half = tid&1 (112 of KPAD=224 per lane).
//  - Weights (W1*mask, W2*mask, Wa+Wb) pre-folded to f16 pairs in VGPRs.
//  - Per tick: 14 x (ds_read_b128 broadcast + 12 v_dot2_f32_f16) per lane,
//    pair-combine via __shfl_xor(.,1), fast tanh/sigmoid (exp2+rcp), blend.
//  - Layers pipelined across timesteps (layer l computes tick-l) -> ONE
//    __syncthreads per tick. Ping-pong f16 xcat in LDS. x prefetched 2 ahead.
// VALU floor ~672 cyc/tick -> 287us; predict 380-480us.
// ============================================================================

typedef _Float16 half2v __attribute__((ext_vector_type(2)));
typedef _Float16 half8v __attribute__((ext_vector_type(8)));

#define NBLK   256
#define NTHR   512
#define TSTEPS 1024
#define KPAD   224
#define KHALF  112
#define NKB    14      // KHALF / 8 blocks per lane

struct Ptrs {
    const float* x;
    const unsigned int* msk[3];   // bool in reference -> int32 on device
    const float* W1[3];
    const float* W2[3];
    const float* Wa[3];
    const float* Wb[3];
    const float* b1[3];
    const float* b2[3];
    const float* ba[3];
    const float* bb[3];
    const float* fcW;
    const float* fcb;
};

__device__ __forceinline__ float fexp2(float x) {
#if __has_builtin(__builtin_amdgcn_exp2f)
    return __builtin_amdgcn_exp2f(x);
#else
    return exp2f(x);
#endif
}
__device__ __forceinline__ float frcp(float x) {
#if __has_builtin(__builtin_amdgcn_rcpf)
    return __builtin_amdgcn_rcpf(x);
#else
    return 1.0f / x;
#endif
}
// sigmoid(x) = 1/(1+2^(-x*log2e)); tanh(x) = 2/(1+2^(-2x*log2e)) - 1
__device__ __forceinline__ float fsig(float x) {
    return frcp(1.0f + fexp2(-1.442695041f * x));
}
__device__ __forceinline__ float ftanh(float x) {
    return 2.0f * frcp(1.0f + fexp2(-2.885390082f * x)) - 1.0f;
}

#if __has_builtin(__builtin_amdgcn_fdot2)
#define FD(a, b, c) __builtin_amdgcn_fdot2((a), (b), (c), false)
#else
__device__ __forceinline__ float fd_fallback(half2v a, half2v b, float c) {
    return c + (float)a[0] * (float)b[0] + (float)a[1] * (float)b[1];
}
#define FD(a, b, c) fd_fallback((a), (b), (c))
#endif

__global__ __launch_bounds__(NTHR)
__attribute__((amdgpu_waves_per_eu(2, 2)))
void cfc_kernel(Ptrs P, float* __restrict__ out) {
    // xc[parity][layer][k] : f16 concat inputs per layer, zero-padded to KPAD.
    __shared__ __align__(16) _Float16 xc[2][3][KPAD];
    __shared__ __align__(16) float hn[256];

    const int tid  = threadIdx.x;
    const int b    = blockIdx.x;
    const int pair = tid >> 1;   // output unit 0..255
    const int half = tid & 1;    // which K-half this lane owns

    // ---- pair role: one output unit ----
    int L, n;
    if (pair < 135)      { L = 0; n = pair; }
    else if (pair < 224) { L = 1; n = pair - 135; }
    else                 { L = 2; n = pair - 224; }
    const int K    = (L == 0) ? 199 : ((L == 1) ? 224 : 121);
    const int HOFF = (L == 0) ? 0   : ((L == 1) ? 135 : 224);

    // ---- zero LDS (padding regions must read as 0.0) ----
    {
        int* z = (int*)&xc[0][0][0];
        for (int i = tid; i < 2 * 3 * KPAD / 2; i += NTHR) z[i] = 0;
    }
    __syncthreads();

    // ---- x staging: threads 448..511 own one of the 64 input features ----
    const int xlane = tid - 448;
    float xpend = 0.0f;
    if (xlane >= 0) {
        xc[0][0][xlane] = (_Float16)P.x[((size_t)b * TSTEPS + 0) * 64 + xlane];
        xpend           = P.x[((size_t)b * TSTEPS + 1) * 64 + xlane];
    }

    // ---- weight preload: this lane's K-half; fold mask, fold Wa+Wb; f16 ----
    const float* W1p        = P.W1[L];
    const float* W2p        = P.W2[L];
    const float* Wap        = P.Wa[L];
    const float* Wbp        = P.Wb[L];
    const unsigned int* mkp = P.msk[L];
    const int nK   = n * K;
    const int koff = half * KHALF;

    half2v wr1[KHALF / 2], wr2[KHALF / 2], wra[KHALF / 2];
#pragma unroll
    for (int i = 0; i < KHALF / 2; ++i) {
        const int k0 = koff + 2 * i, k1 = koff + 2 * i + 1;
        float u0 = 0.f, u1 = 0.f, v0 = 0.f, v1 = 0.f, a0 = 0.f, a1 = 0.f;
        if (k0 < K) {
            const int idx = nK + k0;
            const float mm = (mkp[idx] != 0u) ? 1.0f : 0.0f;
            u0 = W1p[idx] * mm;
            v0 = W2p[idx] * mm;
            a0 = Wap[idx] + Wbp[idx];
        }
        if (k1 < K) {
            const int idx = nK + k1;
            const float mm = (mkp[idx] != 0u) ? 1.0f : 0.0f;
            u1 = W1p[idx] * mm;
            v1 = W2p[idx] * mm;
            a1 = Wap[idx] + Wbp[idx];
        }
        wr1[i] = half2v{(_Float16)u0, (_Float16)u1};
        wr2[i] = half2v{(_Float16)v0, (_Float16)v1};
        wra[i] = half2v{(_Float16)a0, (_Float16)a1};
    }
    const float bv1 = P.b1[L][n];
    const float bv2 = P.b2[L][n];
    const float bva = P.ba[L][n] + P.bb[L][n];
    __syncthreads();

    // ---- main scan: layer L computes timestep (tick - L); 1 barrier/tick ----
    for (int tick = 0; tick < TSTEPS + 2; ++tick) {
        // stage x(tick+1) (loaded 1 tick ago), prefetch x(tick+2)
        if (xlane >= 0) {
            if (tick + 1 < TSTEPS)
                xc[(tick + 1) & 1][0][xlane] = (_Float16)xpend;
            if (tick + 2 < TSTEPS)
                xpend = P.x[((size_t)b * TSTEPS + (tick + 2)) * 64 + xlane];
        }

        const int s = tick - L;
        if (s >= 0 && s < TSTEPS) {
            const _Float16* src = &xc[s & 1][L][koff];
            float ac00 = 0.f, ac01 = 0.f, ac10 = 0.f, ac11 = 0.f, ac20 = 0.f, ac21 = 0.f;
#pragma unroll
            for (int kb = 0; kb < NKB; ++kb) {
                const half8v xv = *(const half8v*)(src + kb * 8);
                const half2v x0 = {xv[0], xv[1]};
                const half2v x1 = {xv[2], xv[3]};
                const half2v x2 = {xv[4], xv[5]};
                const half2v x3 = {xv[6], xv[7]};
                const int k4 = kb * 4;
                ac00 = FD(x0, wr1[k4 + 0], ac00);
                ac10 = FD(x0, wr2[k4 + 0], ac10);
                ac20 = FD(x0, wra[k4 + 0], ac20);
                ac01 = FD(x1, wr1[k4 + 1], ac01);
                ac11 = FD(x1, wr2[k4 + 1], ac11);
                ac21 = FD(x1, wra[k4 + 1], ac21);
                ac00 = FD(x2, wr1[k4 + 2], ac00);
                ac10 = FD(x2, wr2[k4 + 2], ac10);
                ac20 = FD(x2, wra[k4 + 2], ac20);
                ac01 = FD(x3, wr1[k4 + 3], ac01);
                ac11 = FD(x3, wr2[k4 + 3], ac11);
                ac21 = FD(x3, wra[k4 + 3], ac21);
            }
            // combine the two K-halves (pairs are adjacent lanes in-wave)
            float s1 = ac00 + ac01;
            float s2 = ac10 + ac11;
            float sa = ac20 + ac21;
            s1 += __shfl_xor(s1, 1, 64);
            s2 += __shfl_xor(s2, 1, 64);
            sa += __shfl_xor(sa, 1, 64);
            // both lanes now hold identical sums -> identical h
            const float f1 = ftanh(s1 + bv1);
            const float f2 = ftanh(s2 + bv2);
            const float tg = fsig(sa + bva);
            const float h  = f1 + tg * (f2 - f1);
            const _Float16 hv = (_Float16)h;

            const int pA = s & 1;        // consumer at timestep s (next layer)
            const int pB = (s + 1) & 1;  // consumer at timestep s+1 (own recurrence)
            // split the two stores across the lane pair
            if (half == 0) {
                if (L == 0)      xc[pA][1][n] = hv;        // -> layer1 input part
                else if (L == 1) xc[pA][2][n] = hv;        // -> layer2 input part
                if (s == TSTEPS - 1) hn[HOFF + n] = h;     // fp32 final state
            } else {
                if (L == 0)      xc[pB][0][64 + n]  = hv;  // own recurrence
                else if (L == 1) xc[pB][1][135 + n] = hv;
                else             xc[pB][2][89 + n]  = hv;
            }
        }
        __syncthreads();
    }

    // ---- FC epilogue: out[b][o] = dot(hn, fcW[o,:]) + fcb[o], K-split pair ----
    {
        const int o = pair;
        const float4* wr = (const float4*)(P.fcW + (size_t)o * 256 + half * 128);
        const float4* hr = (const float4*)(hn + half * 128);
        float acc = half ? 0.0f : P.fcb[o];
#pragma unroll 8
        for (int d = 0; d < 32; ++d) {
            const float4 a = hr[d];
            const float4 w = wr[d];
            acc += a.x * w.x + a.y * w.y + a.z * w.z + a.w * w.w;
        }
        acc += __shfl_xor(acc, 1, 64);
        if (half == 0) out[(size_t)b * 256 + o] = acc;
    }
}

extern "C" void kernel_launch(void* const* d_in, const int* in_sizes, int n_in,
                              void* d_out, int out_size, void* d_ws, size_t ws_size,
                              hipStream_t stream) {
    (void)in_sizes; (void)n_in; (void)out_size; (void)d_ws; (void)ws_size;
    Ptrs P;
    P.x = (const float*)d_in[0];
    for (int l = 0; l < 3; ++l) {
        const int base = 1 + l * 9;
        P.msk[l] = (const unsigned int*)d_in[base + 0];
        P.W1[l]  = (const float*)d_in[base + 1];
        P.W2[l]  = (const float*)d_in[base + 2];
        P.Wa[l]  = (const float*)d_in[base + 3];
        P.Wb[l]  = (const float*)d_in[base + 4];
        P.b1[l]  = (const float*)d_in[base + 5];
        P.b2[l]  = (const float*)d_in[base + 6];
        P.ba[l]  = (const float*)d_in[base + 7];
        P.bb[l]  = (const float*)d_in[base + 8];
    }
    P.fcW = (const float*)d_in[28];
    P.fcb = (const float*)d_in[29];

    hipLaunchKernelGGL(cfc_kernel, dim3(NBLK), dim3(NTHR), 0, stream,
                       P, (float*)d_out);
}